// Round 3
// baseline (163.458 us; speedup 1.0000x reference)
//
#include <hip/hip_runtime.h>
#include <math.h>
#include <stdint.h>

#define B_  16
#define N_  512
#define C_  384
#define K_  64
#define NN_ (N_*N_)   // 262144

typedef short bf16x8 __attribute__((ext_vector_type(8)));
typedef float f32x4  __attribute__((ext_vector_type(4)));

// fp32 -> bf16 round-to-nearest-even (inputs finite, no NaN path needed)
__device__ __forceinline__ unsigned short f2bf(float f) {
    union { float f; unsigned u; } v; v.f = f;
    unsigned r = v.u + 0x7FFF + ((v.u >> 16) & 1);
    return (unsigned short)(r >> 16);
}
__device__ __forceinline__ unsigned pack2(float a, float b) {
    return ((unsigned)f2bf(b) << 16) | f2bf(a);
}

// async 16-B global -> LDS (lane-contiguous LDS dest required)
__device__ __forceinline__ void gl_lds16(const void* g, void* l) {
    __builtin_amdgcn_global_load_lds(
        (const __attribute__((address_space(1))) unsigned*)g,
        (__attribute__((address_space(3))) unsigned*)l, 16, 0, 0);
}

__device__ __forceinline__ void fma4(float4& c, float s, const float4& v) {
    c.x = fmaf(s, v.x, c.x);
    c.y = fmaf(s, v.y, c.y);
    c.z = fmaf(s, v.z, c.z);
    c.w = fmaf(s, v.w, c.w);
}

// ---------------------------------------------------------------------------
// 1) partial sums part[b][s][c] = sum over 16 rows (no atomics, no memset)
//    + emit x as bf16.  grid (32,16), block 384.
// ---------------------------------------------------------------------------
__global__ __launch_bounds__(384) void mean_kernel(const float* __restrict__ x,
                                                   float* __restrict__ part,
                                                   unsigned short* __restrict__ xb) {
    const int b = blockIdx.y;
    const int s = blockIdx.x;      // n-chunk of 16
    const int c = threadIdx.x;     // 0..383
    const size_t base = ((size_t)(b * N_ + s * 16)) * C_ + c;
    const float* xp = x + base;
    unsigned short* xo = xb + base;
    float acc = 0.f;
#pragma unroll
    for (int i = 0; i < 16; ++i) {
        float v = xp[(size_t)i * C_];
        acc += v;
        xo[(size_t)i * C_] = f2bf(v);
    }
    part[((size_t)b * 32 + s) * C_ + c] = acc;
}

// ---------------------------------------------------------------------------
// 2) reduce partials -> q, then attn[b,k] = softmax_k(cosine(q, centers[:,k]))
//    grid 16, block 384 (6 waves).  Wave 0 does the 64-wide softmax.
// ---------------------------------------------------------------------------
__global__ __launch_bounds__(384) void attn_kernel(const float* __restrict__ part,
                                                   const float* __restrict__ centers,
                                                   float* __restrict__ attn) {
    __shared__ float q_lds[C_];
    __shared__ float red[6];
    const int b = blockIdx.x;
    const int tid = threadIdx.x;

    // phase 1: q[c] = sum of 32 partials; per-wave |q|^2 partials
    const float* pb = part + (size_t)b * 32 * C_ + tid;
    float s = 0.f;
#pragma unroll
    for (int i = 0; i < 32; ++i) s += pb[(size_t)i * C_];
    q_lds[tid] = s;
    float p2 = s * s;
#pragma unroll
    for (int off = 32; off > 0; off >>= 1) p2 += __shfl_xor(p2, off);
    if ((tid & 63) == 0) red[tid >> 6] = p2;
    __syncthreads();

    // phase 2: wave 0 only
    if (tid < 64) {
        const int k = tid;
        const float qn2 = red[0] + red[1] + red[2] + red[3] + red[4] + red[5];
        const float qnorm = fmaxf(sqrtf(qn2), 1e-12f);

        float dot = 0.f, cn2 = 0.f;
        for (int c = 0; c < C_; ++c) {
            float sv = centers[c * K_ + k];   // coalesced across lanes
            float qc = q_lds[c];              // LDS broadcast
            dot = fmaf(qc, sv, dot);
            cn2 = fmaf(sv, sv, cn2);
        }
        const float logit = dot / (qnorm * fmaxf(sqrtf(cn2), 1e-12f));

        float m = logit;
#pragma unroll
        for (int off = 32; off > 0; off >>= 1) m = fmaxf(m, __shfl_xor(m, off));
        const float e = expf(logit - m);
        float ssum = e;
#pragma unroll
        for (int off = 32; off > 0; off >>= 1) ssum += __shfl_xor(ssum, off);
        attn[b * K_ + k] = e / ssum;
    }
}

// ---------------------------------------------------------------------------
// 3) tm[b,:,:] = sum_k attn[b,k] * tran_ms[k,:,:]  -> bf16
//    attn staged in LDS as [k][b] so each k-iter is 4x ds_read_b128.
//    grid 256, block 256; one float4 of (n,m) per thread, 16 batch accs.
// ---------------------------------------------------------------------------
__global__ __launch_bounds__(256) void tm_kernel(const float* __restrict__ tran,
                                                 const float* __restrict__ attn,
                                                 unsigned short* __restrict__ tmb) {
    __shared__ float a_s[K_ * B_];   // [k][b]
    const int tid = threadIdx.x;
    for (int i = tid; i < K_ * B_; i += 256)
        a_s[i] = attn[(i & 15) * K_ + (i >> 4)];
    __syncthreads();

    const size_t j = ((size_t)blockIdx.x * 256 + tid) * 4;
    float4 acc[B_];
#pragma unroll
    for (int b = 0; b < B_; ++b) acc[b] = make_float4(0.f, 0.f, 0.f, 0.f);

    for (int k = 0; k < K_; ++k) {
        const float4 t = *(const float4*)(tran + (size_t)k * NN_ + j);
        const float4* wp = (const float4*)(a_s + k * 16);
        const float4 w0 = wp[0], w1 = wp[1], w2 = wp[2], w3 = wp[3];
        fma4(acc[0],  w0.x, t); fma4(acc[1],  w0.y, t);
        fma4(acc[2],  w0.z, t); fma4(acc[3],  w0.w, t);
        fma4(acc[4],  w1.x, t); fma4(acc[5],  w1.y, t);
        fma4(acc[6],  w1.z, t); fma4(acc[7],  w1.w, t);
        fma4(acc[8],  w2.x, t); fma4(acc[9],  w2.y, t);
        fma4(acc[10], w2.z, t); fma4(acc[11], w2.w, t);
        fma4(acc[12], w3.x, t); fma4(acc[13], w3.y, t);
        fma4(acc[14], w3.z, t); fma4(acc[15], w3.w, t);
    }
#pragma unroll
    for (int b = 0; b < B_; ++b) {
        *(uint2*)(tmb + (size_t)b * NN_ + j) =
            make_uint2(pack2(acc[b].x, acc[b].y), pack2(acc[b].z, acc[b].w));
    }
}

// ---------------------------------------------------------------------------
// 4) xw = x @ W^T (bf16 MFMA), W converted fp32->bf16 in-kernel during staging.
//    Output transposed per batch: xwT[b][c][m] bf16.
//    grid (128, 6), block 256 (4 waves, 2x2 of 32x32 wave tiles).
// ---------------------------------------------------------------------------
__global__ __launch_bounds__(256) void xw_mfma(const unsigned short* __restrict__ Xb,
                                               const float* __restrict__ Wf,
                                               unsigned short* __restrict__ xwT) {
    __shared__ unsigned short As[64 * 64];
    __shared__ unsigned short Bs[64 * 64];
    __shared__ float T[4][32 * 35];   // per-wave transpose staging

    const int tid  = threadIdx.x;
    const int row0 = blockIdx.x * 64;
    const int col0 = blockIdx.y * 64;
    const int lane = tid & 63;
    const int w    = tid >> 6;
    const int wm   = w & 1, wn = w >> 1;
    const int quad = lane >> 4, l15 = lane & 15;

    const int sm = tid >> 3;   // staging row within half-tile
    const int sc = tid & 7;    // staging chunk slot

    f32x4 acc[2][2] = {};

    for (int k0 = 0; k0 < C_; k0 += 64) {
        // W fp32 loads into regs (no LDS hazard -> issue before barrier)
        float4 wv[2][2];
#pragma unroll
        for (int p = 0; p < 2; ++p) {
            const int m  = p * 32 + sm;
            const int gc = sc ^ (m & 7);
            const float* src = Wf + (size_t)(col0 + m) * C_ + k0 + gc * 8;
            wv[p][0] = *(const float4*)(src);
            wv[p][1] = *(const float4*)(src + 4);
        }
        __syncthreads();
#pragma unroll
        for (int p = 0; p < 2; ++p) {
            const int m  = p * 32 + sm;
            const int gc = sc ^ (m & 7);
            gl_lds16(Xb + (size_t)(row0 + m) * C_ + k0 + gc * 8,
                     As + (p * 256 + tid) * 8);
            const uint4 u = make_uint4(pack2(wv[p][0].x, wv[p][0].y),
                                       pack2(wv[p][0].z, wv[p][0].w),
                                       pack2(wv[p][1].x, wv[p][1].y),
                                       pack2(wv[p][1].z, wv[p][1].w));
            *(uint4*)(Bs + (p * 256 + tid) * 8) = u;
        }
        __syncthreads();
#pragma unroll
        for (int kk = 0; kk < 2; ++kk) {
            bf16x8 afr[2], bfr[2];
#pragma unroll
            for (int mt = 0; mt < 2; ++mt) {
                const int mr = wm * 32 + mt * 16 + l15;
                const int kc = (kk * 4 + quad) ^ (mr & 7);
                afr[mt] = *(const bf16x8*)(As + mr * 64 + kc * 8);
            }
#pragma unroll
            for (int nt = 0; nt < 2; ++nt) {
                const int nr = wn * 32 + nt * 16 + l15;
                const int kc = (kk * 4 + quad) ^ (nr & 7);
                bfr[nt] = *(const bf16x8*)(Bs + nr * 64 + kc * 8);
            }
#pragma unroll
            for (int mt = 0; mt < 2; ++mt)
#pragma unroll
                for (int nt = 0; nt < 2; ++nt)
                    acc[mt][nt] = __builtin_amdgcn_mfma_f32_16x16x32_bf16(
                        afr[mt], bfr[nt], acc[mt][nt], 0, 0, 0);
        }
    }

    // transpose epilogue: write bf16 xwT[b][c][m]
#pragma unroll
    for (int mt = 0; mt < 2; ++mt)
#pragma unroll
        for (int nt = 0; nt < 2; ++nt)
#pragma unroll
            for (int r = 0; r < 4; ++r)
                T[w][(mt * 16 + quad * 4 + r) * 35 + nt * 16 + l15] = acc[mt][nt][r];
    __syncthreads();

    const int rw = row0 + wm * 32;
    const int b  = rw >> 9;
    const int m0 = rw & 511;
    const int c0 = col0 + wn * 32;
    unsigned short* dst = xwT + (size_t)b * C_ * N_;
#pragma unroll
    for (int i = 0; i < 8; ++i) {
        const int cl = i * 4 + quad;
        const int ml = l15 * 2;
        const float v0 = T[w][(ml + 0) * 35 + cl];
        const float v1 = T[w][(ml + 1) * 35 + cl];
        *(unsigned*)(dst + (size_t)(c0 + cl) * N_ + m0 + ml) = pack2(v0, v1);
    }
}

// ---------------------------------------------------------------------------
// 5) out[b,n,c] = sum_m tm[b,n,m] * xw[b,m,c] + bias[c]  (bf16 MFMA, fp32 out)
//    grid (8, 6, 16), block 256.
// ---------------------------------------------------------------------------
__global__ __launch_bounds__(256) void out_mfma(const unsigned short* __restrict__ Ab,
                                                const unsigned short* __restrict__ Bt,
                                                const float* __restrict__ bias,
                                                float* __restrict__ out) {
    __shared__ unsigned short As[64 * 64];
    __shared__ unsigned short Bs[64 * 64];

    const int tid  = threadIdx.x;
    const int b    = blockIdx.z;
    const int row0 = blockIdx.x * 64;
    const int col0 = blockIdx.y * 64;
    const int lane = tid & 63;
    const int w    = tid >> 6;
    const int wm   = w & 1, wn = w >> 1;
    const int quad = lane >> 4, l15 = lane & 15;

    const unsigned short* Abase = Ab + (size_t)b * N_ * N_;
    const unsigned short* Bbase = Bt + (size_t)b * C_ * N_;

    const int sm = tid >> 3;
    const int sc = tid & 7;

    f32x4 acc[2][2] = {};

    for (int k0 = 0; k0 < N_; k0 += 64) {
        __syncthreads();
#pragma unroll
        for (int p = 0; p < 2; ++p) {
            const int m  = p * 32 + sm;
            const int gc = sc ^ (m & 7);
            gl_lds16(Abase + (size_t)(row0 + m) * N_ + k0 + gc * 8,
                     As + (p * 256 + tid) * 8);
            gl_lds16(Bbase + (size_t)(col0 + m) * N_ + k0 + gc * 8,
                     Bs + (p * 256 + tid) * 8);
        }
        __syncthreads();
#pragma unroll
        for (int kk = 0; kk < 2; ++kk) {
            bf16x8 afr[2], bfr[2];
#pragma unroll
            for (int mt = 0; mt < 2; ++mt) {
                const int mr = wm * 32 + mt * 16 + l15;
                const int kc = (kk * 4 + quad) ^ (mr & 7);
                afr[mt] = *(const bf16x8*)(As + mr * 64 + kc * 8);
            }
#pragma unroll
            for (int nt = 0; nt < 2; ++nt) {
                const int nr = wn * 32 + nt * 16 + l15;
                const int kc = (kk * 4 + quad) ^ (nr & 7);
                bfr[nt] = *(const bf16x8*)(Bs + nr * 64 + kc * 8);
            }
#pragma unroll
            for (int mt = 0; mt < 2; ++mt)
#pragma unroll
                for (int nt = 0; nt < 2; ++nt)
                    acc[mt][nt] = __builtin_amdgcn_mfma_f32_16x16x32_bf16(
                        afr[mt], bfr[nt], acc[mt][nt], 0, 0, 0);
        }
    }

#pragma unroll
    for (int nt = 0; nt < 2; ++nt) {
        const int c  = col0 + wn * 32 + nt * 16 + l15;
        const float bv = bias[c];
#pragma unroll
        for (int mt = 0; mt < 2; ++mt) {
            const int rbase = row0 + wm * 32 + mt * 16 + quad * 4;
#pragma unroll
            for (int r = 0; r < 4; ++r)
                out[((size_t)(b * N_ + rbase + r)) * C_ + c] = acc[mt][nt][r] + bv;
        }
    }
}

// ---------------------------------------------------------------------------
// launch — 5 dispatches, no memset, no atomics
// ---------------------------------------------------------------------------
extern "C" void kernel_launch(void* const* d_in, const int* in_sizes, int n_in,
                              void* d_out, int out_size, void* d_ws, size_t ws_size,
                              hipStream_t stream) {
    const float* x       = (const float*)d_in[0];   // [16,512,384]
    const float* centers = (const float*)d_in[1];   // [384,64]
    const float* tran    = (const float*)d_in[2];   // [64,512,512]
    const float* proj_w  = (const float*)d_in[3];   // [384,384]
    const float* proj_b  = (const float*)d_in[4];   // [384]
    float* out = (float*)d_out;                     // [16,512,384]

    float* ws   = (float*)d_ws;
    float* part = ws;                                    // 16*32*384 = 196608 fl
    float* attn = ws + 196608;                           // 1024 fl
    unsigned short* tmb = (unsigned short*)(ws + 197632);        // 16*512*512 bf16
    unsigned short* xwT = tmb + (size_t)B_ * N_ * N_;            // 16*384*512 bf16
    unsigned short* xb  = xwT + (size_t)B_ * C_ * N_;            // 16*512*384 bf16

    mean_kernel<<<dim3(32, 16), 384, 0, stream>>>(x, part, xb);
    attn_kernel<<<16, 384, 0, stream>>>(part, centers, attn);
    tm_kernel<<<256, 256, 0, stream>>>(tran, attn, tmb);
    xw_mfma<<<dim3(128, 6), 256, 0, stream>>>(xb, proj_w, xwT);
    out_mfma<<<dim3(8, 6, 16), 256, 0, stream>>>(tmb, xwT, proj_b, out);
}

// Round 4
// 151.385 us; speedup vs baseline: 1.0798x; 1.0798x over previous
//
#include <hip/hip_runtime.h>
#include <math.h>
#include <stdint.h>

#define B_  16
#define N_  512
#define C_  384
#define K_  64
#define NN_ (N_*N_)   // 262144

typedef short bf16x8 __attribute__((ext_vector_type(8)));
typedef float f32x4  __attribute__((ext_vector_type(4)));

// fp32 -> bf16 round-to-nearest-even (inputs finite, no NaN path needed)
__device__ __forceinline__ unsigned short f2bf(float f) {
    union { float f; unsigned u; } v; v.f = f;
    unsigned r = v.u + 0x7FFF + ((v.u >> 16) & 1);
    return (unsigned short)(r >> 16);
}
__device__ __forceinline__ unsigned pack2(float a, float b) {
    return ((unsigned)f2bf(b) << 16) | f2bf(a);
}

// async 16-B global -> LDS (lane-contiguous LDS dest required)
__device__ __forceinline__ void gl_lds16(const void* g, void* l) {
    __builtin_amdgcn_global_load_lds(
        (const __attribute__((address_space(1))) unsigned*)g,
        (__attribute__((address_space(3))) unsigned*)l, 16, 0, 0);
}

__device__ __forceinline__ void fma4(float4& c, float s, const float4& v) {
    c.x = fmaf(s, v.x, c.x);
    c.y = fmaf(s, v.y, c.y);
    c.z = fmaf(s, v.z, c.z);
    c.w = fmaf(s, v.w, c.w);
}

// ---------------------------------------------------------------------------
// 1) partial sums part[b][s][c] = sum over 16 rows + emit x as bf16
// ---------------------------------------------------------------------------
__global__ __launch_bounds__(384) void mean_kernel(const float* __restrict__ x,
                                                   float* __restrict__ part,
                                                   unsigned short* __restrict__ xb) {
    const int b = blockIdx.y;
    const int s = blockIdx.x;
    const int c = threadIdx.x;
    const size_t base = ((size_t)(b * N_ + s * 16)) * C_ + c;
    const float* xp = x + base;
    unsigned short* xo = xb + base;
    float acc = 0.f;
#pragma unroll
    for (int i = 0; i < 16; ++i) {
        float v = xp[(size_t)i * C_];
        acc += v;
        xo[(size_t)i * C_] = f2bf(v);
    }
    part[((size_t)b * 32 + s) * C_ + c] = acc;
}

// ---------------------------------------------------------------------------
// 2) reduce partials -> q; attn[b,k] = softmax_k(cosine(q, centers[:,k]))
// ---------------------------------------------------------------------------
__global__ __launch_bounds__(384) void attn_kernel(const float* __restrict__ part,
                                                   const float* __restrict__ centers,
                                                   float* __restrict__ attn) {
    __shared__ float q_lds[C_];
    __shared__ float red[6];
    const int b = blockIdx.x;
    const int tid = threadIdx.x;

    const float* pb = part + (size_t)b * 32 * C_ + tid;
    float s = 0.f;
#pragma unroll
    for (int i = 0; i < 32; ++i) s += pb[(size_t)i * C_];
    q_lds[tid] = s;
    float p2 = s * s;
#pragma unroll
    for (int off = 32; off > 0; off >>= 1) p2 += __shfl_xor(p2, off);
    if ((tid & 63) == 0) red[tid >> 6] = p2;
    __syncthreads();

    if (tid < 64) {
        const int k = tid;
        const float qn2 = red[0] + red[1] + red[2] + red[3] + red[4] + red[5];
        const float qnorm = fmaxf(sqrtf(qn2), 1e-12f);

        float dot = 0.f, cn2 = 0.f;
        for (int c = 0; c < C_; ++c) {
            float sv = centers[c * K_ + k];
            float qc = q_lds[c];
            dot = fmaf(qc, sv, dot);
            cn2 = fmaf(sv, sv, cn2);
        }
        const float logit = dot / (qnorm * fmaxf(sqrtf(cn2), 1e-12f));

        float m = logit;
#pragma unroll
        for (int off = 32; off > 0; off >>= 1) m = fmaxf(m, __shfl_xor(m, off));
        const float e = expf(logit - m);
        float ssum = e;
#pragma unroll
        for (int off = 32; off > 0; off >>= 1) ssum += __shfl_xor(ssum, off);
        attn[b * K_ + k] = e / ssum;
    }
}

// ---------------------------------------------------------------------------
// 3+4 fused) blocks [0,256):  tm[b,:,:] = sum_k attn[b,k]*tran[k]  -> bf16
//            blocks [256,1024): xw = x @ W^T (bf16 MFMA) -> xwT[b][c][m]
//    tm is HBM-bound, xw is MFMA-bound -> co-scheduling overlaps the pipes.
// ---------------------------------------------------------------------------
__global__ __launch_bounds__(256) void tmxw_kernel(const float* __restrict__ tran,
                                                   const float* __restrict__ attn,
                                                   unsigned short* __restrict__ tmb,
                                                   const unsigned short* __restrict__ Xb,
                                                   const float* __restrict__ Wf,
                                                   unsigned short* __restrict__ xwT) {
    __shared__ unsigned short As[64 * 64];
    __shared__ unsigned short Bs[64 * 64];
    __shared__ float T[4][32 * 35];

    const int tid = threadIdx.x;

    if (blockIdx.x < 256) {
        // ------------------- tm path -------------------
        float* a_s = (float*)As;   // [k][b], 1024 floats
        for (int i = tid; i < K_ * B_; i += 256)
            a_s[i] = attn[(i & 15) * K_ + (i >> 4)];
        __syncthreads();

        const size_t j = ((size_t)blockIdx.x * 256 + tid) * 4;
        float4 acc[B_];
#pragma unroll
        for (int b = 0; b < B_; ++b) acc[b] = make_float4(0.f, 0.f, 0.f, 0.f);

        for (int k = 0; k < K_; k += 2) {
            const float4 t0 = *(const float4*)(tran + (size_t)k * NN_ + j);
            const float4 t1 = *(const float4*)(tran + (size_t)(k + 1) * NN_ + j);
            {
                const float4* wp = (const float4*)(a_s + k * 16);
                const float4 w0 = wp[0], w1 = wp[1], w2 = wp[2], w3 = wp[3];
                fma4(acc[0],  w0.x, t0); fma4(acc[1],  w0.y, t0);
                fma4(acc[2],  w0.z, t0); fma4(acc[3],  w0.w, t0);
                fma4(acc[4],  w1.x, t0); fma4(acc[5],  w1.y, t0);
                fma4(acc[6],  w1.z, t0); fma4(acc[7],  w1.w, t0);
                fma4(acc[8],  w2.x, t0); fma4(acc[9],  w2.y, t0);
                fma4(acc[10], w2.z, t0); fma4(acc[11], w2.w, t0);
                fma4(acc[12], w3.x, t0); fma4(acc[13], w3.y, t0);
                fma4(acc[14], w3.z, t0); fma4(acc[15], w3.w, t0);
            }
            {
                const float4* wp = (const float4*)(a_s + (k + 1) * 16);
                const float4 w0 = wp[0], w1 = wp[1], w2 = wp[2], w3 = wp[3];
                fma4(acc[0],  w0.x, t1); fma4(acc[1],  w0.y, t1);
                fma4(acc[2],  w0.z, t1); fma4(acc[3],  w0.w, t1);
                fma4(acc[4],  w1.x, t1); fma4(acc[5],  w1.y, t1);
                fma4(acc[6],  w1.z, t1); fma4(acc[7],  w1.w, t1);
                fma4(acc[8],  w2.x, t1); fma4(acc[9],  w2.y, t1);
                fma4(acc[10], w2.z, t1); fma4(acc[11], w2.w, t1);
                fma4(acc[12], w3.x, t1); fma4(acc[13], w3.y, t1);
                fma4(acc[14], w3.z, t1); fma4(acc[15], w3.w, t1);
            }
        }
#pragma unroll
        for (int b = 0; b < B_; ++b)
            *(uint2*)(tmb + (size_t)b * NN_ + j) =
                make_uint2(pack2(acc[b].x, acc[b].y), pack2(acc[b].z, acc[b].w));
        return;
    }

    // ------------------- xw path -------------------
    const int bid  = blockIdx.x - 256;      // [0,768)
    const int row0 = (bid & 127) * 64;
    const int col0 = (bid >> 7) * 64;
    const int lane = tid & 63;
    const int w    = tid >> 6;
    const int wm   = w & 1, wn = w >> 1;
    const int quad = lane >> 4, l15 = lane & 15;

    const int sm = tid >> 3;
    const int sc = tid & 7;

    f32x4 acc[2][2] = {};

    for (int k0 = 0; k0 < C_; k0 += 64) {
        float4 wv[2][2];
#pragma unroll
        for (int p = 0; p < 2; ++p) {
            const int m  = p * 32 + sm;
            const int gc = sc ^ (m & 7);
            const float* src = Wf + (size_t)(col0 + m) * C_ + k0 + gc * 8;
            wv[p][0] = *(const float4*)(src);
            wv[p][1] = *(const float4*)(src + 4);
        }
        __syncthreads();
#pragma unroll
        for (int p = 0; p < 2; ++p) {
            const int m  = p * 32 + sm;
            const int gc = sc ^ (m & 7);
            gl_lds16(Xb + (size_t)(row0 + m) * C_ + k0 + gc * 8,
                     As + (p * 256 + tid) * 8);
            *(uint4*)(Bs + (p * 256 + tid) * 8) =
                make_uint4(pack2(wv[p][0].x, wv[p][0].y),
                           pack2(wv[p][0].z, wv[p][0].w),
                           pack2(wv[p][1].x, wv[p][1].y),
                           pack2(wv[p][1].z, wv[p][1].w));
        }
        __syncthreads();
#pragma unroll
        for (int kk = 0; kk < 2; ++kk) {
            bf16x8 afr[2], bfr[2];
#pragma unroll
            for (int mt = 0; mt < 2; ++mt) {
                const int mr = wm * 32 + mt * 16 + l15;
                const int kc = (kk * 4 + quad) ^ (mr & 7);
                afr[mt] = *(const bf16x8*)(As + mr * 64 + kc * 8);
            }
#pragma unroll
            for (int nt = 0; nt < 2; ++nt) {
                const int nr = wn * 32 + nt * 16 + l15;
                const int kc = (kk * 4 + quad) ^ (nr & 7);
                bfr[nt] = *(const bf16x8*)(Bs + nr * 64 + kc * 8);
            }
#pragma unroll
            for (int mt = 0; mt < 2; ++mt)
#pragma unroll
                for (int nt = 0; nt < 2; ++nt)
                    acc[mt][nt] = __builtin_amdgcn_mfma_f32_16x16x32_bf16(
                        afr[mt], bfr[nt], acc[mt][nt], 0, 0, 0);
        }
    }

#pragma unroll
    for (int mt = 0; mt < 2; ++mt)
#pragma unroll
        for (int nt = 0; nt < 2; ++nt)
#pragma unroll
            for (int r = 0; r < 4; ++r)
                T[w][(mt * 16 + quad * 4 + r) * 35 + nt * 16 + l15] = acc[mt][nt][r];
    __syncthreads();

    const int rw = row0 + wm * 32;
    const int b  = rw >> 9;
    const int m0 = rw & 511;
    const int c0 = col0 + wn * 32;
    unsigned short* dst = xwT + (size_t)b * C_ * N_;
#pragma unroll
    for (int i = 0; i < 8; ++i) {
        const int cl = i * 4 + quad;
        const int ml = l15 * 2;
        const float v0 = T[w][(ml + 0) * 35 + cl];
        const float v1 = T[w][(ml + 1) * 35 + cl];
        *(unsigned*)(dst + (size_t)(c0 + cl) * N_ + m0 + ml) = pack2(v0, v1);
    }
}

// ---------------------------------------------------------------------------
// 5) out[b,n,c] = sum_m tm[b,n,m] * xw[b,m,c] + bias[c]  (bf16 MFMA, fp32 out)
// ---------------------------------------------------------------------------
__global__ __launch_bounds__(256) void out_mfma(const unsigned short* __restrict__ Ab,
                                                const unsigned short* __restrict__ Bt,
                                                const float* __restrict__ bias,
                                                float* __restrict__ out) {
    __shared__ unsigned short As[64 * 64];
    __shared__ unsigned short Bs[64 * 64];

    const int tid  = threadIdx.x;
    const int b    = blockIdx.z;
    const int row0 = blockIdx.x * 64;
    const int col0 = blockIdx.y * 64;
    const int lane = tid & 63;
    const int w    = tid >> 6;
    const int wm   = w & 1, wn = w >> 1;
    const int quad = lane >> 4, l15 = lane & 15;

    const unsigned short* Abase = Ab + (size_t)b * N_ * N_;
    const unsigned short* Bbase = Bt + (size_t)b * C_ * N_;

    const int sm = tid >> 3;
    const int sc = tid & 7;

    f32x4 acc[2][2] = {};

    for (int k0 = 0; k0 < N_; k0 += 64) {
        __syncthreads();
#pragma unroll
        for (int p = 0; p < 2; ++p) {
            const int m  = p * 32 + sm;
            const int gc = sc ^ (m & 7);
            gl_lds16(Abase + (size_t)(row0 + m) * N_ + k0 + gc * 8,
                     As + (p * 256 + tid) * 8);
            gl_lds16(Bbase + (size_t)(col0 + m) * N_ + k0 + gc * 8,
                     Bs + (p * 256 + tid) * 8);
        }
        __syncthreads();
#pragma unroll
        for (int kk = 0; kk < 2; ++kk) {
            bf16x8 afr[2], bfr[2];
#pragma unroll
            for (int mt = 0; mt < 2; ++mt) {
                const int mr = wm * 32 + mt * 16 + l15;
                const int kc = (kk * 4 + quad) ^ (mr & 7);
                afr[mt] = *(const bf16x8*)(As + mr * 64 + kc * 8);
            }
#pragma unroll
            for (int nt = 0; nt < 2; ++nt) {
                const int nr = wn * 32 + nt * 16 + l15;
                const int kc = (kk * 4 + quad) ^ (nr & 7);
                bfr[nt] = *(const bf16x8*)(Bs + nr * 64 + kc * 8);
            }
#pragma unroll
            for (int mt = 0; mt < 2; ++mt)
#pragma unroll
                for (int nt = 0; nt < 2; ++nt)
                    acc[mt][nt] = __builtin_amdgcn_mfma_f32_16x16x32_bf16(
                        afr[mt], bfr[nt], acc[mt][nt], 0, 0, 0);
        }
    }

#pragma unroll
    for (int nt = 0; nt < 2; ++nt) {
        const int c  = col0 + wn * 32 + nt * 16 + l15;
        const float bv = bias[c];
#pragma unroll
        for (int mt = 0; mt < 2; ++mt) {
            const int rbase = row0 + wm * 32 + mt * 16 + quad * 4;
#pragma unroll
            for (int r = 0; r < 4; ++r)
                out[((size_t)(b * N_ + rbase + r)) * C_ + c] = acc[mt][nt][r] + bv;
        }
    }
}

// ---------------------------------------------------------------------------
// launch — 4 dispatches
// ---------------------------------------------------------------------------
extern "C" void kernel_launch(void* const* d_in, const int* in_sizes, int n_in,
                              void* d_out, int out_size, void* d_ws, size_t ws_size,
                              hipStream_t stream) {
    const float* x       = (const float*)d_in[0];   // [16,512,384]
    const float* centers = (const float*)d_in[1];   // [384,64]
    const float* tran    = (const float*)d_in[2];   // [64,512,512]
    const float* proj_w  = (const float*)d_in[3];   // [384,384]
    const float* proj_b  = (const float*)d_in[4];   // [384]
    float* out = (float*)d_out;                     // [16,512,384]

    float* ws   = (float*)d_ws;
    float* part = ws;                                    // 16*32*384 floats
    float* attn = ws + 196608;                           // 1024 floats
    unsigned short* tmb = (unsigned short*)(ws + 197632);        // 16*512*512 bf16
    unsigned short* xwT = tmb + (size_t)B_ * N_ * N_;            // 16*384*512 bf16
    unsigned short* xb  = xwT + (size_t)B_ * C_ * N_;            // 16*512*384 bf16

    mean_kernel<<<dim3(32, 16), 384, 0, stream>>>(x, part, xb);
    attn_kernel<<<16, 384, 0, stream>>>(part, centers, attn);
    tmxw_kernel<<<1024, 256, 0, stream>>>(tran, attn, tmb, xb, proj_w, xwT);
    out_mfma<<<dim3(8, 6, 16), 256, 0, stream>>>(tmb, xwT, proj_b, out);
}